// Round 2
// baseline (176.654 us; speedup 1.0000x reference)
//
#include <hip/hip_runtime.h>
#include <cstdint>
#include <cstddef>

#define BT_TOTAL 76800   // 128*600 cells
#define NCLS 13
#define IGN  (-100)

#define CPB   8                       // cells per chunk
#define NCH   8                       // chunks per block
#define NTHR  64                      // ONE wave per block -> no barriers anywhere
#define CELLS_PER_BLK (CPB * NCH)     // 64
#define NBLK  (BT_TOTAL / CELLS_PER_BLK)   // 1200 blocks; 30.7KB LDS -> 5/CU -> all resident

#define NF4T  (CPB * 195 / 4)   // 390 float4 of target per chunk
#define KT    7                 // ceil(390/64) padded rounds
#define PADT  (KT * 64)         // 448
#define NF4P  (CPB * 234 / 4)   // 468 float4 of pred per chunk
#define KP    8                 // ceil(468/64)
#define PADP  (KP * 64)         // 512
// DMA ops per chunk per thread = KT + KP = 15 (wave-uniform: tail addresses clamped)

struct Partial { float ls; int lc; int cor; int val; };

// async global->LDS DMA, 16B per lane; LDS dest = wave-uniform base + lane*16
__device__ __forceinline__ void stage16(const float4* g, float4* l) {
    __builtin_amdgcn_global_load_lds((const __attribute__((address_space(1))) void*)g,
                                     (__attribute__((address_space(3))) void*)l,
                                     16, 0, 0);
}

// issue all 15 DMA ops for one chunk; every thread issues exactly 15 (clamped tails)
__device__ __forceinline__ void issue_chunk(const float* __restrict__ target,
                                            const float* __restrict__ pred,
                                            int cell0, float4* bT, float4* bP, int lane) {
    const float4* gt = (const float4*)(target + (size_t)cell0 * 195);
#pragma unroll
    for (int r = 0; r < KT; r++) {
        const int i  = r * 64 + lane;
        const int ic = (i < NF4T) ? i : (NF4T - 1);   // clamp global src; LDS dest stays linear
        stage16(gt + ic, bT + i);
    }
    const float4* gp = (const float4*)(pred + (size_t)cell0 * 234);
#pragma unroll
    for (int r = 0; r < KP; r++) {
        const int i  = r * 64 + lane;
        const int ic = (i < NF4P) ? i : (NF4P - 1);
        stage16(gp + ic, bP + i);
    }
}

extern "C" __global__ __launch_bounds__(NTHR)
void tdoa_fused(const float* __restrict__ pred, const float* __restrict__ target,
                Partial* __restrict__ part) {
    const int lane     = threadIdx.x;
    const int cellbase = blockIdx.x * CELLS_PER_BLK;

    __shared__ float4 sT0[PADT], sT1[PADT];   // 2 x 7168 B
    __shared__ float4 sP0[PADP], sP1[PADP];   // 2 x 8192 B  -> total 30720 B

    float lsum = 0.f;
    int   lcnt = 0, cor = 0, nval = 0;

    // prologue: chunk 0 in flight
    issue_chunk(target, pred, cellbase, sT0, sP0, lane);

#pragma unroll
    for (int k = 0; k < NCH; k++) {
        float4*      nT = (k & 1) ? sT0 : sT1;
        float4*      nP = (k & 1) ? sP0 : sP1;
        const float* cT = (const float*)((k & 1) ? sT1 : sT0);
        const float* cP = (const float*)((k & 1) ? sP1 : sP0);

        if (k + 1 < NCH) {
            issue_chunk(target, pred, cellbase + (k + 1) * CPB, nT, nP, lane);
            // chunk k's 15 ops are the oldest; waiting vmcnt(15) completes them
            // while chunk k+1's 15 ops stay in flight across the whole compute phase.
            asm volatile("s_waitcnt vmcnt(15)" ::: "memory");
        } else {
            asm volatile("s_waitcnt vmcnt(0)" ::: "memory");
        }
        __builtin_amdgcn_sched_barrier(0);

        // ---- phase A: TDOA per (cell, track), 24 lanes ----
        uint32_t tdw = 0;
        {
            const int cellA = lane / 3;          // 0..7 for lane<24
            const int e     = lane - cellA * 3;  // track
            if (lane < 24) {
                const float* tg = cT + cellA * 195 + e * 65;
                float a[NCLS];
#pragma unroll
                for (int c = 0; c < NCLS; c++) a[c] = tg[c];
                bool ia = false;
#pragma unroll
                for (int c = 0; c < NCLS; c++) ia = ia || (a[c] > 0.0f);
                float d0 = 0.f, d1 = 0.f, d2 = 0.f, ds = 0.f;
#pragma unroll
                for (int c = 0; c < NCLS; c++) {
                    d0 += a[c] * tg[13 + c];
                    d1 += a[c] * tg[26 + c];
                    d2 += a[c] * tg[39 + c];
                    ds += a[c] * tg[52 + c];
                }
                const float sx = d0 * ds, sy = d1 * ds, sz = d2 * ds;
                const float MX[4] = { 0.02432757455f,  0.02432757455f, -0.02432757455f, -0.02432757455f };
                const float MY[4] = { 0.02432757455f, -0.02432757455f,  0.02432757455f, -0.02432757455f };
                const float MZ[4] = { 0.02409021033f, -0.02409021033f, -0.02409021033f,  0.02409021033f };
                float dm[4];
#pragma unroll
                for (int m = 0; m < 4; m++) {
                    const float ex = sx - MX[m], ey = sy - MY[m], ez = sz - MZ[m];
                    dm[m] = sqrtf(ex * ex + ey * ey + ez * ez);
                }
                const int PI_[6] = {0,0,0,1,1,2};
                const int PJ_[6] = {1,2,3,2,3,3};
                uint32_t w = 0;
#pragma unroll
                for (int p = 0; p < 6; p++) {
                    int t = (int)rintf((dm[PI_[p]] - dm[PJ_[p]]) * (24000.0f / 343.0f)) + 6;
                    t = (t < 0) ? 0 : ((t > 12) ? 12 : t);   // tdoa in [0,12] by triangle ineq.
                    w |= ((uint32_t)t) << (4 * p);
                }
                if (ia) w |= (1u << 28);
                tdw = w;
            }
        }

        // cross-lane handoff (all lanes active for the shuffles)
        const int btl48 = (lane < 48) ? (lane / 6) : 0;
        const uint32_t t0 = __shfl(tdw, btl48 * 3 + 0, 64);
        const uint32_t t1 = __shfl(tdw, btl48 * 3 + 1, 64);
        const uint32_t t2 = __shfl(tdw, btl48 * 3 + 2, 64);

        // ---- phase B: one lane per (cell, pair), 48 lanes ----
        if (lane < 48) {
            const int btl = lane / 6;
            const int p   = lane - btl * 6;

            // reconstruct ta/tb from packed track words
            const bool ab0 = (t0 >> 28) & 1, ab1 = (t1 >> 28) & 1, ab2 = (t2 >> 28) & 1;
            const int  nact = (int)ab0 + (int)ab1 + (int)ab2;
            const int  v0 = (int)((t0 >> (4 * p)) & 15);
            const int  v1 = (int)((t1 >> (4 * p)) & 15);
            const int  v2 = (int)((t2 >> (4 * p)) & 15);
            const int  g0 = ab0 ? v0 : (ab1 ? v1 : v2);
            const int  g1 = (ab0 && ab1) ? v1 : v2;
            const int  g2 = v2;
            int ta[3], tb[3];
            ta[0] = g0;
            ta[1] = (nact >= 2) ? g1 : g0;
            ta[2] = (nact == 3) ? g2 : ((nact == 2) ? g1 : g0);
            tb[0] = g0;
            tb[1] = (nact >= 2) ? g1 : g0;
            tb[2] = (nact == 3) ? g2 : g0;
            if (nact == 0) { ta[0]=ta[1]=ta[2]=IGN; tb[0]=tb[1]=tb[2]=IGN; }

            const float* pp = cP + btl * 234 + p;   // [c][tr][p] strides 18,6,1

            float x[NCLS][3];
#pragma unroll
            for (int c = 0; c < NCLS; c++)
#pragma unroll
                for (int j = 0; j < 3; j++)
                    x[c][j] = pp[c * 18 + j * 6];

            int   am[3];
            float lse[3];
#pragma unroll
            for (int j = 0; j < 3; j++) {
                float m = x[0][j]; int a = 0;
#pragma unroll
                for (int c = 1; c < NCLS; c++) { if (x[c][j] > m) { m = x[c][j]; a = c; } }
                float s = 0.f;
#pragma unroll
                for (int c = 0; c < NCLS; c++) s += expf(x[c][j] - m);
                am[j] = a; lse[j] = m + logf(s);
            }

            // indexed LDS reads instead of 13-deep cndmask select chains
            float La[3][3], Lb[3][3];
#pragma unroll
            for (int i = 0; i < 3; i++) {
                const int  ca  = (ta[i] < 0) ? 0 : ta[i];
                const int  cbb = (tb[i] < 0) ? 0 : tb[i];
                const bool ia2 = (ta[i] == IGN);
                const bool ib2 = (tb[i] == IGN);
#pragma unroll
                for (int j = 0; j < 3; j++) {
                    La[i][j] = ia2 ? 0.f : (lse[j] - pp[ca  * 18 + j * 6]);
                    Lb[i][j] = ib2 ? 0.f : (lse[j] - pp[cbb * 18 + j * 6]);
                }
            }

            const int P0[6] = {0,0,1,1,2,2};
            const int P1[6] = {1,2,0,2,0,1};
            const int P2[6] = {2,1,2,0,1,0};
            float l1 = 0.f, l2 = 0.f; int i1 = 0, i2 = 0;
#pragma unroll
            for (int q = 0; q < 6; q++) {
                const float va = (La[0][P0[q]] + La[1][P1[q]] + La[2][P2[q]]) * (1.0f / 3.0f);
                const float vb = (Lb[0][P0[q]] + Lb[1][P1[q]] + Lb[2][P2[q]]) * (1.0f / 3.0f);
                if (q == 0) { l1 = va; l2 = vb; }
                else {
                    if (va < l1) { l1 = va; i1 = q; }
                    if (vb < l2) { l2 = vb; i2 = q; }
                }
            }

            const bool use2 = (l2 < l1);
            const float loss = use2 ? l2 : l1;
            const int  qsel = use2 ? i2 : i1;
            const int PK[6] = {36, 24, 33, 9, 18, 6};   // p0 | p1<<2 | p2<<4
            int pk = PK[0];
#pragma unroll
            for (int kk = 1; kk < 6; kk++) pk = (qsel == kk) ? PK[kk] : pk;
            const int s0 = use2 ? tb[0] : ta[0];
            const int s1 = use2 ? tb[1] : ta[1];
            const int s2 = use2 ? tb[2] : ta[2];
#pragma unroll
            for (int i = 0; i < 3; i++) {
                const int pi = (pk >> (2 * i)) & 3;
                const int tp = (pi == 0) ? s0 : ((pi == 1) ? s1 : s2);
                const bool v = (tp != IGN);
                nval += v ? 1 : 0;
                cor  += (v && (am[i] == tp)) ? 1 : 0;
            }
            if (loss > 0.f) { lsum += loss; lcnt++; }
        }
    }

    // single-wave reduction -> per-block partial
#pragma unroll
    for (int off = 32; off > 0; off >>= 1) {
        lsum += __shfl_down(lsum, off, 64);
        lcnt += __shfl_down(lcnt, off, 64);
        cor  += __shfl_down(cor,  off, 64);
        nval += __shfl_down(nval, off, 64);
    }
    if (lane == 0) {
        Partial pt; pt.ls = lsum; pt.lc = lcnt; pt.cor = cor; pt.val = nval;
        part[blockIdx.x] = pt;
    }
}

// ================= Final reduce =================
extern "C" __global__ __launch_bounds__(256)
void tdoa_final(const Partial* __restrict__ part, float* __restrict__ out) {
    const int tid = threadIdx.x;
    double ls = 0.0; int lc = 0, cor = 0, val = 0;
    for (int i = tid; i < NBLK; i += 256) {
        const Partial p = part[i];
        ls += (double)p.ls; lc += p.lc; cor += p.cor; val += p.val;
    }
#pragma unroll
    for (int off = 32; off > 0; off >>= 1) {
        ls  += __shfl_down(ls,  off, 64);
        lc  += __shfl_down(lc,  off, 64);
        cor += __shfl_down(cor, off, 64);
        val += __shfl_down(val, off, 64);
    }
    __shared__ double sd[4];
    __shared__ int    s1[4], s2[4], s3[4];
    const int wid = tid >> 6;
    if ((tid & 63) == 0) { sd[wid] = ls; s1[wid] = lc; s2[wid] = cor; s3[wid] = val; }
    __syncthreads();
    if (tid == 0) {
        const double L = sd[0] + sd[1] + sd[2] + sd[3];
        const int c1 = s1[0] + s1[1] + s1[2] + s1[3];
        const int c2 = s2[0] + s2[1] + s2[2] + s2[3];
        const int c3 = s3[0] + s3[1] + s3[2] + s3[3];
        out[0] = (c1 > 0) ? (float)(L / (double)c1) : 0.0f;
        out[1] = (c3 > 0) ? ((float)c2 / (float)c3) : 0.0f;
    }
}

extern "C" void kernel_launch(void* const* d_in, const int* in_sizes, int n_in,
                              void* d_out, int out_size, void* d_ws, size_t ws_size,
                              hipStream_t stream) {
    const float* pred   = (const float*)d_in[0];
    const float* target = (const float*)d_in[1];
    Partial* part = (Partial*)d_ws;   // 1200 * 16 B of scratch
    float* out = (float*)d_out;
    hipLaunchKernelGGL(tdoa_fused, dim3(NBLK), dim3(NTHR), 0, stream, pred, target, part);
    hipLaunchKernelGGL(tdoa_final, dim3(1),    dim3(256), 0, stream, part, out);
}